// Round 1
// 326.217 us; speedup vs baseline: 1.0032x; 1.0032x over previous
//
#include <hip/hip_runtime.h>

// Problem constants (from reference)
#define BB 32
#define HH 128
#define WW 512
#define CC 32
#define OUT_H 64
#define OUT_W 256

// Native vector type (clang ext_vector) — accepted by __builtin_nontemporal_*
typedef float vfloat4 __attribute__((ext_vector_type(4)));

// Two vertically-adjacent output pixels per thread (rows i, i+1; same j).
// 8 consecutive lanes = one output pixel's 32 channels (128 B contiguous).
// Doubles in-flight gather loads per thread (4 -> 8) to cover L2/HBM latency;
// amortizes theta/grid setup; when |t4| is small the two pixels' input rows
// overlap -> L1 hits on half the gathers. Stores stay two contiguous 1 KiB
// runs per wave, written non-temporally so the write-once stream does not
// evict gather-reuse lines from L2.
__global__ __launch_bounds__(256) void bilin_kernel(
    const vfloat4* __restrict__ img4,
    const float* __restrict__ theta,
    vfloat4* __restrict__ out4)
{
    const int gid = blockIdx.x * blockDim.x + threadIdx.x;
    const int c4 = gid & 7;              // float4 slot within the 32 channels
    const int s  = gid >> 3;             // slot: b*(OUT_H/2)*OUT_W + i2*OUT_W + j
    const int j  = s & (OUT_W - 1);
    const int i2 = (s >> 8) & (OUT_H / 2 - 1);
    const int b  = s >> 13;
    const int i0 = i2 * 2;               // rows i0 and i0+1

    // b is wave-uniform (16 pixels/wave, batch = 8192 slots) -> scalarize
    const int bu = __builtin_amdgcn_readfirstlane(b);
    float t0 = theta[bu * 6 + 0];
    float t1 = theta[bu * 6 + 1];
    float t2 = theta[bu * 6 + 2];
    float t3 = theta[bu * 6 + 3];
    float t4 = theta[bu * 6 + 4];
    float t5 = theta[bu * 6 + 5];
    // reference's debug hack
    if (bu == 0) { t3 = 0.0f; t4 = 0.0f; t5 = 0.0f; }
    if (bu == 1) { t0 = 0.0f; t1 = 0.0f; t2 = 0.0f; }

    // sampling grid in [-1,1]
    const float xg  = -1.0f + 2.0f * (float)j * (1.0f / 255.0f);
    const float yg0 = -1.0f + 2.0f * (float)i0 * (1.0f / 63.0f);
    const float yg1 = yg0 + 2.0f / 63.0f;

    // --- pixel 0 (row i0) coordinates ---
    const float xA = 0.5f * (t0 * xg + t1 * yg0 + t2 + 1.0f) * (float)WW;
    const float yA = 0.5f * (t3 * xg + t4 * yg0 + t5 + 1.0f) * (float)HH;
    // --- pixel 1 (row i0+1) coordinates ---
    const float xB = 0.5f * (t0 * xg + t1 * yg1 + t2 + 1.0f) * (float)WW;
    const float yB = 0.5f * (t3 * xg + t4 * yg1 + t5 + 1.0f) * (float)HH;

    // trunc toward zero, then clip; weights use CLIPPED coords (per ref)
    int ax0 = (int)xA, ay0 = (int)yA;
    int ax1 = ax0 + 1, ay1 = ay0 + 1;
    ax0 = min(max(ax0, 0), WW - 1);
    ax1 = min(max(ax1, 0), WW - 1);
    ay0 = min(max(ay0, 0), HH - 1);
    ay1 = min(max(ay1, 0), HH - 1);

    int bx0 = (int)xB, by0 = (int)yB;
    int bx1 = bx0 + 1, by1 = by0 + 1;
    bx0 = min(max(bx0, 0), WW - 1);
    bx1 = min(max(bx1, 0), WW - 1);
    by0 = min(max(by0, 0), HH - 1);
    by1 = min(max(by1, 0), HH - 1);

    // float4 indices (image is 16,777,216 float4s -> int math safe)
    const int base = bu * (HH * WW * (CC / 4));

    // Issue all 8 gathers up front for maximum MLP.
    const vfloat4 pA0 = img4[base + (ay0 * WW + ax0) * (CC / 4) + c4];
    const vfloat4 pB0 = img4[base + (ay1 * WW + ax0) * (CC / 4) + c4];
    const vfloat4 pC0 = img4[base + (ay0 * WW + ax1) * (CC / 4) + c4];
    const vfloat4 pD0 = img4[base + (ay1 * WW + ax1) * (CC / 4) + c4];

    const vfloat4 pA1 = img4[base + (by0 * WW + bx0) * (CC / 4) + c4];
    const vfloat4 pB1 = img4[base + (by1 * WW + bx0) * (CC / 4) + c4];
    const vfloat4 pC1 = img4[base + (by0 * WW + bx1) * (CC / 4) + c4];
    const vfloat4 pD1 = img4[base + (by1 * WW + bx1) * (CC / 4) + c4];

    // weights (clipped-coordinate semantics, per reference)
    const float ax0f = (float)ax0, ax1f = (float)ax1;
    const float ay0f = (float)ay0, ay1f = (float)ay1;
    const float wA0 = (ax1f - xA) * (ay1f - yA);
    const float wB0 = (ax1f - xA) * (yA - ay0f);
    const float wC0 = (xA - ax0f) * (ay1f - yA);
    const float wD0 = (xA - ax0f) * (yA - ay0f);

    const float bx0f = (float)bx0, bx1f = (float)bx1;
    const float by0f = (float)by0, by1f = (float)by1;
    const float wA1 = (bx1f - xB) * (by1f - yB);
    const float wB1 = (bx1f - xB) * (yB - by0f);
    const float wC1 = (xB - bx0f) * (by1f - yB);
    const float wD1 = (xB - bx0f) * (yB - by0f);

    const vfloat4 o0 = pA0 * wA0 + pB0 * wB0 + pC0 * wC0 + pD0 * wD0;
    const vfloat4 o1 = pA1 * wA1 + pB1 * wB1 + pC1 * wC1 + pD1 * wD1;

    // non-temporal: keep the write-once output stream out of L2
    const int outIdx0 = ((b * OUT_H + i0) * OUT_W + j) * (CC / 4) + c4;
    __builtin_nontemporal_store(o0, &out4[outIdx0]);
    __builtin_nontemporal_store(o1, &out4[outIdx0 + OUT_W * (CC / 4)]);
}

extern "C" void kernel_launch(void* const* d_in, const int* in_sizes, int n_in,
                              void* d_out, int out_size, void* d_ws, size_t ws_size,
                              hipStream_t stream) {
    const vfloat4* img4 = (const vfloat4*)d_in[0];
    const float* theta = (const float*)d_in[1];
    vfloat4* out4 = (vfloat4*)d_out;

    const int total_threads = BB * (OUT_H / 2) * OUT_W * (CC / 4); // 2,097,152
    const int block = 256;
    const int grid = total_threads / block;                        // 8,192
    bilin_kernel<<<grid, block, 0, stream>>>(img4, theta, out4);
}